// Round 11
// baseline (68.717 us; speedup 1.0000x reference)
//
#include <hip/hip_runtime.h>

// Problem constants (fixed by setup_inputs)
#define B   8
#define C   256
#define H   128
#define W   128
#define HW  (H * W)
#define FH  512
#define FW  512

// Tiling
#define TR     16              // output rows per tile
#define SLOTS  24              // staged row slots (rows row0..row0+23, clamped)
#define HALO   3               // rows staged above tile: row0 = ybase-3
#define CG     8               // channels per block (4 interleaved pairs)
#define NPAIR  (CG / 2)        // 4
#define RGN    (H / TR)        // 8 row-groups
#define CGN    (C / CG)        // 32 channel-groups

typedef float f32x4v __attribute__((ext_vector_type(4)));
typedef float f32x2v __attribute__((ext_vector_type(2)));

// ---------------------------------------------------------------------------
// Kernel 1: strided 4x4 conv downsample of flows using runtime conv_w.
// ---------------------------------------------------------------------------
__global__ __launch_bounds__(256) void downsample_kernel(
    const float* __restrict__ flows,
    const float* __restrict__ conv_w,
    float* __restrict__ f)
{
    int idx = blockIdx.x * blockDim.x + threadIdx.x;
    if (idx >= B * 2 * H * W) return;
    int x = idx & (W - 1);
    int y = (idx >> 7) & (H - 1);
    int o = (idx >> 14) & 1;
    int b = idx >> 15;

    const float* fb = flows + (size_t)b * 2 * FH * FW;
    const float* cw = conv_w + o * 2 * 16;

    float acc = 0.f;
#pragma unroll
    for (int i = 0; i < 2; ++i) {
        const float* fi = fb + (size_t)i * FH * FW;
#pragma unroll
        for (int kh = 0; kh < 4; ++kh) {
            const float4 v = *reinterpret_cast<const float4*>(
                fi + (size_t)(4 * y + kh) * FW + 4 * x);
            const float* w = cw + i * 16 + kh * 4;
            acc += v.x * w[0] + v.y * w[1] + v.z * w[2] + v.w * w[3];
        }
    }
    f[idx] = acc;
}

// ---------------------------------------------------------------------------
// Kernel 2: bilinear warp, channel-PAIRED LDS staging.
// LDS holds float2(chA,chB) per (slot,x): each bilinear tap = one ds_read_b64
// serving two channels; weights/addressing amortized 2x. Per-pixel state in
// named registers. Asm-pinned coalesced prefetch, counted vmcnt (16 compute
// stores newer than the 6 prefetch loads), one barrier per channel pair.
// ---------------------------------------------------------------------------
__global__ __launch_bounds__(256, 3) void warp_kernel(
    const float* __restrict__ feat,
    const float* __restrict__ f,
    float* __restrict__ out)
{
    __shared__ __align__(16) float rows[2][SLOTS * W * 2];  // 2 x 24 KB

    // XCD-chunked swizzle; rg fastest so same-XCD blocks share halo rows.
    const int hw_bid = blockIdx.x;
    const int lin = (hw_bid & 7) * 256 + (hw_bid >> 3);
    const int rg = lin & (RGN - 1);
    const int cg = (lin >> 3) & (CGN - 1);
    const int b  = lin >> 8;

    const int tid = threadIdx.x;
    const int ybase = rg * TR;
    const int row0  = ybase - HALO;
    const int pixbase = ybase * W;

    const float* featb = feat + ((size_t)b * C + (size_t)cg * CG) * HW;
    float*       outc  = out  + ((size_t)b * C + (size_t)cg * CG) * HW + pixbase;
    const float* fx_p  = f + (size_t)(b * 2 + 0) * HW;
    const float* fy_p  = f + (size_t)(b * 2 + 1) * HW;

    // Channel-invariant staging offsets (float units in a channel plane).
    int goff0, goff1, goff2;
    {
        const int c0 = tid,       r0c = min(max(row0 + (c0 >> 5), 0), H - 1);
        const int c1 = 256 + tid, r1c = min(max(row0 + (c1 >> 5), 0), H - 1);
        const int c2 = 512 + tid, r2c = min(max(row0 + (c2 >> 5), 0), H - 1);
        goff0 = r0c * W + (c0 & 31) * 4;
        goff1 = r1c * W + (c1 & 31) * 4;
        goff2 = r2c * W + (c2 & 31) * 4;
    }

    // Staging registers: 3 chunks x 2 channels.
    f32x4v sA0, sA1, sA2, sB0, sB1, sB2;

#define PREF(p) do {                                                          \
        const float* _cA = featb + (size_t)(2 * (p)) * HW;                    \
        const float* _cB = _cA + HW;                                          \
        asm volatile("global_load_dwordx4 %0, %1, off"                        \
                     : "=v"(sA0) : "v"(_cA + goff0) : "memory");              \
        asm volatile("global_load_dwordx4 %0, %1, off"                        \
                     : "=v"(sA1) : "v"(_cA + goff1) : "memory");              \
        asm volatile("global_load_dwordx4 %0, %1, off"                        \
                     : "=v"(sA2) : "v"(_cA + goff2) : "memory");              \
        asm volatile("global_load_dwordx4 %0, %1, off"                        \
                     : "=v"(sB0) : "v"(_cB + goff0) : "memory");              \
        asm volatile("global_load_dwordx4 %0, %1, off"                        \
                     : "=v"(sB1) : "v"(_cB + goff1) : "memory");              \
        asm volatile("global_load_dwordx4 %0, %1, off"                        \
                     : "=v"(sB2) : "v"(_cB + goff2) : "memory");              \
    } while (0)

    // Interleave-write one chunk: paired dest index = plane_index * 2.
#define STASH1(buf, j, ra, rb_) do {                                          \
        float* _d = &rows[(buf)][(((j) * 256 + tid) * 4) * 2];                \
        f32x4v _lo = { ra[0], rb_[0], ra[1], rb_[1] };                        \
        f32x4v _hi = { ra[2], rb_[2], ra[3], rb_[3] };                        \
        *reinterpret_cast<f32x4v*>(_d)     = _lo;                             \
        *reinterpret_cast<f32x4v*>(_d + 4) = _hi;                             \
    } while (0)

#define STASH(buf) do {                                                       \
        STASH1((buf), 0, sA0, sB0);                                           \
        STASH1((buf), 1, sA1, sB1);                                           \
        STASH1((buf), 2, sA2, sB2);                                           \
    } while (0)

    // ---- prologue: pair-0 stage in flight; weights -> registers meanwhile
    PREF(0);

    // Named per-pixel state (no arrays -> guaranteed registers).
#define PXDECL(k) int i0_##k, i1_##k; float w0_##k, w1_##k, w2_##k, w3_##k;
    PXDECL(0) PXDECL(1) PXDECL(2) PXDECL(3)
    PXDECL(4) PXDECL(5) PXDECL(6) PXDECL(7)

#define WCOMP(k) do {                                                         \
        const int px  = tid + ((k) << 8);                                     \
        const int gpx = pixbase + px;                                         \
        const int x = gpx & (W - 1);                                          \
        const int y = gpx >> 7;                                               \
        const float gx = (float)x + fx_p[gpx];                                \
        const float gy = (float)y + fy_p[gpx];                                \
        const float x0f = floorf(gx);                                         \
        const float y0f = floorf(gy);                                         \
        const float wx = gx - x0f;                                            \
        const float wy = gy - y0f;                                            \
        const int x0 = (int)x0f, y0 = (int)y0f;                               \
        const int y1 = y0 + 1;                                                \
        const float u0 = 1.f - wx, u1 = wx;                                   \
        float A, Bv;                                                          \
        if (x0 >= 0 && x0 <= W - 2)      { A = u0;  Bv = u1;  }               \
        else if (x0 == W - 1)            { A = 0.f; Bv = u0;  }               \
        else if (x0 == -1)               { A = u1;  Bv = 0.f; }               \
        else                             { A = 0.f; Bv = 0.f; }               \
        const int bx = min(max(x0, 0), W - 2);                                \
        const float vy0 = (y0 >= 0 && y0 < H) ? 1.f : 0.f;                    \
        const float vy1 = (y1 >= 0 && y1 < H) ? 1.f : 0.f;                    \
        const int cy0 = min(max(y0, 0), H - 1);                               \
        const int cy1 = min(max(y1, 0), H - 1);                               \
        const int s0 = cy0 - row0;                                            \
        const int s1 = cy1 - row0;                                            \
        const bool ok = (s0 >= 0) && (s1 < SLOTS);                            \
        const int cs0 = min(max(s0, 0), SLOTS - 1);                           \
        const int cs1 = min(max(s1, 0), SLOTS - 1);                           \
        i0_##k = (cs0 * W + bx) | (ok ? 0 : (int)0x80000000);                 \
        i1_##k = cs1 * W + bx;                                                \
        const float wy0 = (1.f - wy) * vy0;                                   \
        const float wy1 = wy * vy1;                                           \
        w0_##k = A * wy0;  w1_##k = Bv * wy0;                                 \
        w2_##k = A * wy1;  w3_##k = Bv * wy1;                                 \
    } while (0)

    WCOMP(0); WCOMP(1); WCOMP(2); WCOMP(3);
    WCOMP(4); WCOMP(5); WCOMP(6); WCOMP(7);

    asm volatile("s_waitcnt vmcnt(0)" ::: "memory");
    __builtin_amdgcn_sched_barrier(0);
    STASH(0);
    __syncthreads();

    // Per-pixel compute: 4 paired b64 taps serve BOTH channels.
#define CPX(k, rb, ocA, ocB, chA) do {                                        \
        const int px = tid + ((k) << 8);                                      \
        float vA, vB;                                                         \
        if (__builtin_expect(i0_##k < 0, 0)) {                                \
            const int gpx = pixbase + px;                                     \
            const int x = gpx & (W - 1);                                      \
            const int y = gpx >> 7;                                           \
            const int x0 = (int)floorf((float)x + fx_p[gpx]);                 \
            const int y0 = (int)floorf((float)y + fy_p[gpx]);                 \
            const int bx  = min(max(x0, 0), W - 2);                           \
            const int cy0 = min(max(y0, 0), H - 1);                           \
            const int cy1 = min(max(y0 + 1, 0), H - 1);                       \
            const float* fA = featb + (size_t)(chA) * HW;                     \
            const float* fB = fA + HW;                                        \
            vA = fA[cy0 * W + bx]     * w0_##k + fA[cy0 * W + bx + 1] * w1_##k\
               + fA[cy1 * W + bx]     * w2_##k + fA[cy1 * W + bx + 1] * w3_##k;\
            vB = fB[cy0 * W + bx]     * w0_##k + fB[cy0 * W + bx + 1] * w1_##k\
               + fB[cy1 * W + bx]     * w2_##k + fB[cy1 * W + bx + 1] * w3_##k;\
        } else {                                                              \
            const f32x2v t00 = *reinterpret_cast<const f32x2v*>(              \
                &rb[2 * i0_##k]);                                             \
            const f32x2v t01 = *reinterpret_cast<const f32x2v*>(              \
                &rb[2 * i0_##k + 2]);                                         \
            const f32x2v t10 = *reinterpret_cast<const f32x2v*>(              \
                &rb[2 * i1_##k]);                                             \
            const f32x2v t11 = *reinterpret_cast<const f32x2v*>(              \
                &rb[2 * i1_##k + 2]);                                         \
            vA = t00[0] * w0_##k + t01[0] * w1_##k                            \
               + t10[0] * w2_##k + t11[0] * w3_##k;                           \
            vB = t00[1] * w0_##k + t01[1] * w1_##k                            \
               + t10[1] * w2_##k + t11[1] * w3_##k;                           \
        }                                                                     \
        ocA[px] = vA;                                                         \
        ocB[px] = vB;                                                         \
    } while (0)

    // ---- pair loop: prefetch(p+1) || compute(p) ; stash ; barrier
    for (int p = 0; p < NPAIR; ++p) {
        if (p < NPAIR - 1) PREF(p + 1);

        const float* rb = &rows[p & 1][0];
        float* ocA = outc + (size_t)(2 * p) * HW;
        float* ocB = ocA + HW;
        CPX(0, rb, ocA, ocB, 2 * p); CPX(1, rb, ocA, ocB, 2 * p);
        CPX(2, rb, ocA, ocB, 2 * p); CPX(3, rb, ocA, ocB, 2 * p);
        CPX(4, rb, ocA, ocB, 2 * p); CPX(5, rb, ocA, ocB, 2 * p);
        CPX(6, rb, ocA, ocB, 2 * p); CPX(7, rb, ocA, ocB, 2 * p);

        if (p < NPAIR - 1) {
            // 16 compute stores are newer than PREF's 6 loads -> vmcnt(16)
            // drains exactly the prefetch loads.
            asm volatile("s_waitcnt vmcnt(16)" ::: "memory");
            __builtin_amdgcn_sched_barrier(0);
            STASH((p + 1) & 1);
            __syncthreads();
        }
    }
#undef PREF
#undef STASH
#undef STASH1
#undef PXDECL
#undef WCOMP
#undef CPX
}

// ---------------------------------------------------------------------------
extern "C" void kernel_launch(void* const* d_in, const int* in_sizes, int n_in,
                              void* d_out, int out_size, void* d_ws, size_t ws_size,
                              hipStream_t stream)
{
    const float* features = (const float*)d_in[0];
    const float* flows    = (const float*)d_in[1];
    const float* conv_w   = (const float*)d_in[2];
    float*       out      = (float*)d_out;
    float*       f        = (float*)d_ws;   // [B,2,H,W] = 1 MiB

    downsample_kernel<<<1024, 256, 0, stream>>>(flows, conv_w, f);
    // B * RGN * CGN = 8 * 8 * 32 = 2048 blocks
    warp_kernel<<<2048, 256, 0, stream>>>(features, f, out);
}

// Round 12
// 62.502 us; speedup vs baseline: 1.0994x; 1.0994x over previous
//
#include <hip/hip_runtime.h>

// Problem constants (fixed by setup_inputs)
#define B   8
#define C   256
#define H   128
#define W   128
#define HW  (H * W)
#define FH  512
#define FW  512

// Tiling
#define TR     16              // output rows per tile
#define SLOTS  24              // staged row slots
#define HALO   3               // rows staged above tile: row0 = ybase-3
#define CG     16              // channels per block
#define RGN    (H / TR)        // 8 row-groups
#define CGN    (C / CG)        // 16 channel-groups

typedef float f32x4v __attribute__((ext_vector_type(4)));

// 8B LDS load at 4B alignment -> compiler emits ds_read2_b32 (one instr).
struct __attribute__((packed, aligned(4))) pf2 { float x, y; };

// ---------------------------------------------------------------------------
// Kernel 1: strided 4x4 conv downsample of flows using runtime conv_w.
// ---------------------------------------------------------------------------
__global__ __launch_bounds__(256) void downsample_kernel(
    const float* __restrict__ flows,
    const float* __restrict__ conv_w,
    float* __restrict__ f)
{
    int idx = blockIdx.x * blockDim.x + threadIdx.x;
    if (idx >= B * 2 * H * W) return;
    int x = idx & (W - 1);
    int y = (idx >> 7) & (H - 1);
    int o = (idx >> 14) & 1;
    int b = idx >> 15;

    const float* fb = flows + (size_t)b * 2 * FH * FW;
    const float* cw = conv_w + o * 2 * 16;

    float acc = 0.f;
#pragma unroll
    for (int i = 0; i < 2; ++i) {
        const float* fi = fb + (size_t)i * FH * FW;
#pragma unroll
        for (int kh = 0; kh < 4; ++kh) {
            const float4 v = *reinterpret_cast<const float4*>(
                fi + (size_t)(4 * y + kh) * FW + 4 * x);
            const float* w = cw + i * 16 + kh * 4;
            acc += v.x * w[0] + v.y * w[1] + v.z * w[2] + v.w * w[3];
        }
    }
    f[idx] = acc;
}

// ---------------------------------------------------------------------------
// Kernel 2: bilinear warp. R10 structure (planar LDS row staging, named
// register weights, asm-pinned prefetch, counted vmcnt, 1 barrier/channel)
// + CG=16 (WCOMP amortized 2x) + ds_read2_b32 paired taps + hoisted
// fallback branch (one anybad check per thread per channel).
// ---------------------------------------------------------------------------
__global__ __launch_bounds__(256, 4) void warp_kernel(
    const float* __restrict__ feat,
    const float* __restrict__ f,
    float* __restrict__ out)
{
    __shared__ __align__(16) float rows[2][SLOTS * W];  // 24 KB total

    // XCD-chunked swizzle (1024 blocks = 8 XCDs x 128). rg fastest -> same-XCD
    // blocks share halo rows and flow tiles.
    const int hw_bid = blockIdx.x;
    const int lin = (hw_bid & 7) * 128 + (hw_bid >> 3);
    const int rg = lin & (RGN - 1);
    const int cg = (lin >> 3) & (CGN - 1);
    const int b  = lin >> 7;

    const int tid = threadIdx.x;
    const int ybase = rg * TR;
    const int row0  = ybase - HALO;
    const int pixbase = ybase * W;

    const float* featb = feat + ((size_t)b * C + (size_t)cg * CG) * HW;
    float*       outc  = out  + ((size_t)b * C + (size_t)cg * CG) * HW + pixbase;
    const float* fx_p  = f + (size_t)(b * 2 + 0) * HW;
    const float* fy_p  = f + (size_t)(b * 2 + 1) * HW;

    // Channel-invariant staging offsets (float units).
    int goff0, goff1, goff2;
    {
        const int c0 = tid,       r0c = min(max(row0 + (c0 >> 5), 0), H - 1);
        const int c1 = 256 + tid, r1c = min(max(row0 + (c1 >> 5), 0), H - 1);
        const int c2 = 512 + tid, r2c = min(max(row0 + (c2 >> 5), 0), H - 1);
        goff0 = r0c * W + (c0 & 31) * 4;
        goff1 = r1c * W + (c1 & 31) * 4;
        goff2 = r2c * W + (c2 & 31) * 4;
    }

    f32x4v nx0, nx1, nx2;
#define PREF(ch) do {                                                         \
        const float* _cb = featb + (size_t)(ch) * HW;                         \
        asm volatile("global_load_dwordx4 %0, %1, off"                        \
                     : "=v"(nx0) : "v"(_cb + goff0) : "memory");              \
        asm volatile("global_load_dwordx4 %0, %1, off"                        \
                     : "=v"(nx1) : "v"(_cb + goff1) : "memory");              \
        asm volatile("global_load_dwordx4 %0, %1, off"                        \
                     : "=v"(nx2) : "v"(_cb + goff2) : "memory");              \
    } while (0)

#define STASH(buf) do {                                                       \
        *reinterpret_cast<f32x4v*>(&rows[(buf)][(0 * 256 + tid) * 4]) = nx0;  \
        *reinterpret_cast<f32x4v*>(&rows[(buf)][(1 * 256 + tid) * 4]) = nx1;  \
        *reinterpret_cast<f32x4v*>(&rows[(buf)][(2 * 256 + tid) * 4]) = nx2;  \
    } while (0)

    // ---- prologue: channel-0 stage in flight; weights -> registers meanwhile
    PREF(0);

    // Named per-pixel state (no arrays -> guaranteed registers).
#define PXDECL(k) int i0_##k, i1_##k; float w0_##k, w1_##k, w2_##k, w3_##k;
    PXDECL(0) PXDECL(1) PXDECL(2) PXDECL(3)
    PXDECL(4) PXDECL(5) PXDECL(6) PXDECL(7)

#define WCOMP(k) do {                                                         \
        const int px  = tid + ((k) << 8);                                     \
        const int gpx = pixbase + px;                                         \
        const int x = gpx & (W - 1);                                          \
        const int y = gpx >> 7;                                               \
        const float gx = (float)x + fx_p[gpx];                                \
        const float gy = (float)y + fy_p[gpx];                                \
        const float x0f = floorf(gx);                                         \
        const float y0f = floorf(gy);                                         \
        const float wx = gx - x0f;                                            \
        const float wy = gy - y0f;                                            \
        const int x0 = (int)x0f, y0 = (int)y0f;                               \
        const int y1 = y0 + 1;                                                \
        const float u0 = 1.f - wx, u1 = wx;                                   \
        float A, Bv;                                                          \
        if (x0 >= 0 && x0 <= W - 2)      { A = u0;  Bv = u1;  }               \
        else if (x0 == W - 1)            { A = 0.f; Bv = u0;  }               \
        else if (x0 == -1)               { A = u1;  Bv = 0.f; }               \
        else                             { A = 0.f; Bv = 0.f; }               \
        const int bx = min(max(x0, 0), W - 2);                                \
        const float vy0 = (y0 >= 0 && y0 < H) ? 1.f : 0.f;                    \
        const float vy1 = (y1 >= 0 && y1 < H) ? 1.f : 0.f;                    \
        const int cy0 = min(max(y0, 0), H - 1);                               \
        const int cy1 = min(max(y1, 0), H - 1);                               \
        const int s0 = cy0 - row0;                                            \
        const int s1 = cy1 - row0;                                            \
        const bool ok = (s0 >= 0) && (s1 < SLOTS);                            \
        const int cs0 = min(max(s0, 0), SLOTS - 1);                           \
        const int cs1 = min(max(s1, 0), SLOTS - 1);                           \
        i0_##k = (cs0 * W + bx) | (ok ? 0 : (int)0x80000000);                 \
        i1_##k = cs1 * W + bx;                                                \
        const float wy0 = (1.f - wy) * vy0;                                   \
        const float wy1 = wy * vy1;                                           \
        w0_##k = A * wy0;  w1_##k = Bv * wy0;                                 \
        w2_##k = A * wy1;  w3_##k = Bv * wy1;                                 \
    } while (0)

    WCOMP(0); WCOMP(1); WCOMP(2); WCOMP(3);
    WCOMP(4); WCOMP(5); WCOMP(6); WCOMP(7);

    // One flag per thread: any pixel outside the staged halo?
    const int anybad =
        ((i0_0 | i0_1 | i0_2 | i0_3 | i0_4 | i0_5 | i0_6 | i0_7) < 0);

    asm volatile("s_waitcnt vmcnt(0)" ::: "memory");
    __builtin_amdgcn_sched_barrier(0);
    STASH(0);
    __syncthreads();

    // Fast path: 2 paired LDS taps (ds_read2_b32) + 4 FMA + 1 store.
#define FPX(k, rb, oc) do {                                                   \
        const int px = tid + ((k) << 8);                                      \
        const pf2 t0 = *reinterpret_cast<const pf2*>(&rb[i0_##k]);            \
        const pf2 t1 = *reinterpret_cast<const pf2*>(&rb[i1_##k]);            \
        oc[px] = t0.x * w0_##k + t0.y * w1_##k                                \
               + t1.x * w2_##k + t1.y * w3_##k;                               \
    } while (0)

    // Slow path (never taken for this data): global bilinear gather.
#define SPX(k, oc, ch) do {                                                   \
        const int px = tid + ((k) << 8);                                      \
        const int gpx = pixbase + px;                                         \
        const int x = gpx & (W - 1);                                          \
        const int y = gpx >> 7;                                               \
        const int x0 = (int)floorf((float)x + fx_p[gpx]);                     \
        const int y0 = (int)floorf((float)y + fy_p[gpx]);                     \
        const int bx  = min(max(x0, 0), W - 2);                               \
        const int cy0 = min(max(y0, 0), H - 1);                               \
        const int cy1 = min(max(y0 + 1, 0), H - 1);                           \
        const float* fc = featb + (size_t)(ch) * HW;                          \
        oc[px] = fc[cy0 * W + bx]     * w0_##k + fc[cy0 * W + bx + 1] * w1_##k\
               + fc[cy1 * W + bx]     * w2_##k + fc[cy1 * W + bx + 1] * w3_##k;\
    } while (0)

    // ---- channel loop: prefetch(ch+1) || compute(ch) ; stash ; barrier
    for (int ch = 0; ch < CG; ++ch) {
        if (ch < CG - 1) PREF(ch + 1);

        const float* rb = &rows[ch & 1][0];
        float* oc = outc + (size_t)ch * HW;
        if (__builtin_expect(anybad, 0)) {
            SPX(0, oc, ch); SPX(1, oc, ch); SPX(2, oc, ch); SPX(3, oc, ch);
            SPX(4, oc, ch); SPX(5, oc, ch); SPX(6, oc, ch); SPX(7, oc, ch);
        } else {
            FPX(0, rb, oc); FPX(1, rb, oc); FPX(2, rb, oc); FPX(3, rb, oc);
            FPX(4, rb, oc); FPX(5, rb, oc); FPX(6, rb, oc); FPX(7, rb, oc);
        }

        if (ch < CG - 1) {
            // The 8 compute stores are newer than PREF's 3 loads -> vmcnt(8)
            // waits exactly for the prefetch (extra slow-path loads only add
            // drained slack; still correct).
            asm volatile("s_waitcnt vmcnt(8)" ::: "memory");
            __builtin_amdgcn_sched_barrier(0);
            STASH((ch + 1) & 1);
            __syncthreads();
        }
    }
#undef PREF
#undef STASH
#undef PXDECL
#undef WCOMP
#undef FPX
#undef SPX
}

// ---------------------------------------------------------------------------
extern "C" void kernel_launch(void* const* d_in, const int* in_sizes, int n_in,
                              void* d_out, int out_size, void* d_ws, size_t ws_size,
                              hipStream_t stream)
{
    const float* features = (const float*)d_in[0];
    const float* flows    = (const float*)d_in[1];
    const float* conv_w   = (const float*)d_in[2];
    float*       out      = (float*)d_out;
    float*       f        = (float*)d_ws;   // [B,2,H,W] = 1 MiB

    downsample_kernel<<<1024, 256, 0, stream>>>(flows, conv_w, f);
    // B * RGN * CGN = 8 * 8 * 16 = 1024 blocks
    warp_kernel<<<1024, 256, 0, stream>>>(features, f, out);
}

// Round 13
// 60.686 us; speedup vs baseline: 1.1323x; 1.0299x over previous
//
#include <hip/hip_runtime.h>

// Problem constants (fixed by setup_inputs)
#define B   8
#define C   256
#define H   128
#define W   128
#define HW  (H * W)
#define FH  512
#define FW  512

// Tiling
#define TR     16              // output rows per tile
#define SLOTS  24              // staged row slots
#define HALO   3               // rows staged above tile: row0 = ybase-3
#define SW     132             // padded LDS row stride (floats); 132%32=4 -> row jump shifts banks
#define CG     16              // channels per block (8 pairs)
#define RGN    (H / TR)        // 8 row-groups
#define CGN    (C / CG)        // 16 channel-groups

typedef float f32x4v __attribute__((ext_vector_type(4)));

// 8B LDS load at 4B alignment -> ds_read2_b32 (one instruction).
struct __attribute__((packed, aligned(4))) pf2 { float x, y; };

// ---------------------------------------------------------------------------
// Kernel 1: strided 4x4 conv downsample of flows using runtime conv_w.
// ---------------------------------------------------------------------------
__global__ __launch_bounds__(256) void downsample_kernel(
    const float* __restrict__ flows,
    const float* __restrict__ conv_w,
    float* __restrict__ f)
{
    int idx = blockIdx.x * blockDim.x + threadIdx.x;
    if (idx >= B * 2 * H * W) return;
    int x = idx & (W - 1);
    int y = (idx >> 7) & (H - 1);
    int o = (idx >> 14) & 1;
    int b = idx >> 15;

    const float* fb = flows + (size_t)b * 2 * FH * FW;
    const float* cw = conv_w + o * 2 * 16;

    float acc = 0.f;
#pragma unroll
    for (int i = 0; i < 2; ++i) {
        const float* fi = fb + (size_t)i * FH * FW;
#pragma unroll
        for (int kh = 0; kh < 4; ++kh) {
            const float4 v = *reinterpret_cast<const float4*>(
                fi + (size_t)(4 * y + kh) * FW + 4 * x);
            const float* w = cw + i * 16 + kh * 4;
            acc += v.x * w[0] + v.y * w[1] + v.z * w[2] + v.w * w[3];
        }
    }
    f[idx] = acc;
}

// ---------------------------------------------------------------------------
// Kernel 2: bilinear warp. R12 structure + (a) padded LDS stride SW=132
// (kills row-jump bank conflicts), (b) channel-PAIR super-buffers: one
// barrier per 2 channels (8 vs 16), weights/indices shared across the pair.
// ---------------------------------------------------------------------------
__global__ __launch_bounds__(256, 3) void warp_kernel(
    const float* __restrict__ feat,
    const float* __restrict__ f,
    float* __restrict__ out)
{
    // [super-buffer][channel-within-pair][padded rows]
    __shared__ __align__(16) float rows[2][2][SLOTS * SW];  // 50688 B

    // XCD-chunked swizzle (1024 blocks = 8 XCDs x 128), rg fastest.
    const int hw_bid = blockIdx.x;
    const int lin = (hw_bid & 7) * 128 + (hw_bid >> 3);
    const int rg = lin & (RGN - 1);
    const int cg = (lin >> 3) & (CGN - 1);
    const int b  = lin >> 7;

    const int tid = threadIdx.x;
    const int ybase = rg * TR;
    const int row0  = ybase - HALO;
    const int pixbase = ybase * W;

    const float* featb = feat + ((size_t)b * C + (size_t)cg * CG) * HW;
    float*       outc  = out  + ((size_t)b * C + (size_t)cg * CG) * HW + pixbase;
    const float* fx_p  = f + (size_t)(b * 2 + 0) * HW;
    const float* fy_p  = f + (size_t)(b * 2 + 1) * HW;

    // Channel-invariant staging offsets: global source (goff, W-stride) and
    // LDS dest (soff, SW-stride). 3 chunks per thread, 768 chunks total.
    int goff0, goff1, goff2, soff0, soff1, soff2;
    {
        const int c0 = tid, c1 = 256 + tid, c2 = 512 + tid;
        const int r0c = min(max(row0 + (c0 >> 5), 0), H - 1);
        const int r1c = min(max(row0 + (c1 >> 5), 0), H - 1);
        const int r2c = min(max(row0 + (c2 >> 5), 0), H - 1);
        goff0 = r0c * W + (c0 & 31) * 4;
        goff1 = r1c * W + (c1 & 31) * 4;
        goff2 = r2c * W + (c2 & 31) * 4;
        soff0 = (c0 >> 5) * SW + (c0 & 31) * 4;
        soff1 = (c1 >> 5) * SW + (c1 & 31) * 4;
        soff2 = (c2 >> 5) * SW + (c2 & 31) * 4;
    }

    // Staging registers: 3 chunks x 2 channels of the pair.
    f32x4v nx0, nx1, nx2, mx0, mx1, mx2;

#define PREF2(cA, cB) do {                                                    \
        const float* _pA = featb + (size_t)(cA) * HW;                         \
        const float* _pB = featb + (size_t)(cB) * HW;                         \
        asm volatile("global_load_dwordx4 %0, %1, off"                        \
                     : "=v"(nx0) : "v"(_pA + goff0) : "memory");              \
        asm volatile("global_load_dwordx4 %0, %1, off"                        \
                     : "=v"(nx1) : "v"(_pA + goff1) : "memory");              \
        asm volatile("global_load_dwordx4 %0, %1, off"                        \
                     : "=v"(nx2) : "v"(_pA + goff2) : "memory");              \
        asm volatile("global_load_dwordx4 %0, %1, off"                        \
                     : "=v"(mx0) : "v"(_pB + goff0) : "memory");              \
        asm volatile("global_load_dwordx4 %0, %1, off"                        \
                     : "=v"(mx1) : "v"(_pB + goff1) : "memory");              \
        asm volatile("global_load_dwordx4 %0, %1, off"                        \
                     : "=v"(mx2) : "v"(_pB + goff2) : "memory");              \
    } while (0)

#define STASH2(s) do {                                                        \
        float* _dA = &rows[(s)][0][0];                                        \
        float* _dB = &rows[(s)][1][0];                                        \
        *reinterpret_cast<f32x4v*>(_dA + soff0) = nx0;                        \
        *reinterpret_cast<f32x4v*>(_dA + soff1) = nx1;                        \
        *reinterpret_cast<f32x4v*>(_dA + soff2) = nx2;                        \
        *reinterpret_cast<f32x4v*>(_dB + soff0) = mx0;                        \
        *reinterpret_cast<f32x4v*>(_dB + soff1) = mx1;                        \
        *reinterpret_cast<f32x4v*>(_dB + soff2) = mx2;                        \
    } while (0)

    // ---- prologue: pair-0 stage in flight; weights -> registers meanwhile
    PREF2(0, 1);

    // Named per-pixel state (no arrays -> guaranteed registers).
#define PXDECL(k) int i0_##k, i1_##k; float w0_##k, w1_##k, w2_##k, w3_##k;
    PXDECL(0) PXDECL(1) PXDECL(2) PXDECL(3)
    PXDECL(4) PXDECL(5) PXDECL(6) PXDECL(7)

#define WCOMP(k) do {                                                         \
        const int px  = tid + ((k) << 8);                                     \
        const int gpx = pixbase + px;                                         \
        const int x = gpx & (W - 1);                                          \
        const int y = gpx >> 7;                                               \
        const float gx = (float)x + fx_p[gpx];                                \
        const float gy = (float)y + fy_p[gpx];                                \
        const float x0f = floorf(gx);                                         \
        const float y0f = floorf(gy);                                         \
        const float wx = gx - x0f;                                            \
        const float wy = gy - y0f;                                            \
        const int x0 = (int)x0f, y0 = (int)y0f;                               \
        const int y1 = y0 + 1;                                                \
        const float u0 = 1.f - wx, u1 = wx;                                   \
        float A, Bv;                                                          \
        if (x0 >= 0 && x0 <= W - 2)      { A = u0;  Bv = u1;  }               \
        else if (x0 == W - 1)            { A = 0.f; Bv = u0;  }               \
        else if (x0 == -1)               { A = u1;  Bv = 0.f; }               \
        else                             { A = 0.f; Bv = 0.f; }               \
        const int bx = min(max(x0, 0), W - 2);                                \
        const float vy0 = (y0 >= 0 && y0 < H) ? 1.f : 0.f;                    \
        const float vy1 = (y1 >= 0 && y1 < H) ? 1.f : 0.f;                    \
        const int cy0 = min(max(y0, 0), H - 1);                               \
        const int cy1 = min(max(y1, 0), H - 1);                               \
        const int s0 = cy0 - row0;                                            \
        const int s1 = cy1 - row0;                                            \
        const bool ok = (s0 >= 0) && (s1 < SLOTS);                            \
        const int cs0 = min(max(s0, 0), SLOTS - 1);                           \
        const int cs1 = min(max(s1, 0), SLOTS - 1);                           \
        i0_##k = (cs0 * SW + bx) | (ok ? 0 : (int)0x80000000);                \
        i1_##k = cs1 * SW + bx;                                               \
        const float wy0 = (1.f - wy) * vy0;                                   \
        const float wy1 = wy * vy1;                                           \
        w0_##k = A * wy0;  w1_##k = Bv * wy0;                                 \
        w2_##k = A * wy1;  w3_##k = Bv * wy1;                                 \
    } while (0)

    WCOMP(0); WCOMP(1); WCOMP(2); WCOMP(3);
    WCOMP(4); WCOMP(5); WCOMP(6); WCOMP(7);

    const int anybad =
        ((i0_0 | i0_1 | i0_2 | i0_3 | i0_4 | i0_5 | i0_6 | i0_7) < 0);

    asm volatile("s_waitcnt vmcnt(0)" ::: "memory");
    __builtin_amdgcn_sched_barrier(0);
    STASH2(0);
    __syncthreads();

    // Fast path: 4 paired LDS taps serve BOTH channels (shared weights).
#define FPX2(k, rbA, rbB, ocA, ocB) do {                                      \
        const int px = tid + ((k) << 8);                                      \
        const pf2 a0 = *reinterpret_cast<const pf2*>(&rbA[i0_##k]);           \
        const pf2 a1 = *reinterpret_cast<const pf2*>(&rbA[i1_##k]);           \
        const pf2 b0 = *reinterpret_cast<const pf2*>(&rbB[i0_##k]);           \
        const pf2 b1 = *reinterpret_cast<const pf2*>(&rbB[i1_##k]);           \
        ocA[px] = a0.x * w0_##k + a0.y * w1_##k                               \
                + a1.x * w2_##k + a1.y * w3_##k;                              \
        ocB[px] = b0.x * w0_##k + b0.y * w1_##k                               \
                + b1.x * w2_##k + b1.y * w3_##k;                              \
    } while (0)

    // Slow path (never taken for this data): global bilinear gather, 2 ch.
#define SPX2(k, ocA, ocB, chA) do {                                           \
        const int px = tid + ((k) << 8);                                      \
        const int gpx = pixbase + px;                                         \
        const int x = gpx & (W - 1);                                          \
        const int y = gpx >> 7;                                               \
        const int x0 = (int)floorf((float)x + fx_p[gpx]);                     \
        const int y0 = (int)floorf((float)y + fy_p[gpx]);                     \
        const int bx  = min(max(x0, 0), W - 2);                               \
        const int cy0 = min(max(y0, 0), H - 1);                               \
        const int cy1 = min(max(y0 + 1, 0), H - 1);                           \
        const float* fA = featb + (size_t)(chA) * HW;                         \
        const float* fB = fA + HW;                                            \
        ocA[px] = fA[cy0 * W + bx]     * w0_##k + fA[cy0 * W + bx + 1] * w1_##k\
                + fA[cy1 * W + bx]     * w2_##k + fA[cy1 * W + bx + 1] * w3_##k;\
        ocB[px] = fB[cy0 * W + bx]     * w0_##k + fB[cy0 * W + bx + 1] * w1_##k\
                + fB[cy1 * W + bx]     * w2_##k + fB[cy1 * W + bx + 1] * w3_##k;\
    } while (0)

    // ---- pair loop: prefetch(p+1) || compute(p) ; vmcnt ; stash ; barrier
    for (int p = 0; p < CG / 2; ++p) {
        const int chA = 2 * p;
        if (p < CG / 2 - 1) PREF2(chA + 2, chA + 3);

        const float* rbA = &rows[p & 1][0][0];
        const float* rbB = &rows[p & 1][1][0];
        float* ocA = outc + (size_t)chA * HW;
        float* ocB = ocA + HW;
        if (__builtin_expect(anybad, 0)) {
            SPX2(0, ocA, ocB, chA); SPX2(1, ocA, ocB, chA);
            SPX2(2, ocA, ocB, chA); SPX2(3, ocA, ocB, chA);
            SPX2(4, ocA, ocB, chA); SPX2(5, ocA, ocB, chA);
            SPX2(6, ocA, ocB, chA); SPX2(7, ocA, ocB, chA);
        } else {
            FPX2(0, rbA, rbB, ocA, ocB); FPX2(1, rbA, rbB, ocA, ocB);
            FPX2(2, rbA, rbB, ocA, ocB); FPX2(3, rbA, rbB, ocA, ocB);
            FPX2(4, rbA, rbB, ocA, ocB); FPX2(5, rbA, rbB, ocA, ocB);
            FPX2(6, rbA, rbB, ocA, ocB); FPX2(7, rbA, rbB, ocA, ocB);
        }

        if (p < CG / 2 - 1) {
            // Issue order this iter: 6 loads, then 16 stores -> vmcnt(16)
            // drains exactly the prefetch loads (stores may remain).
            asm volatile("s_waitcnt vmcnt(16)" ::: "memory");
            __builtin_amdgcn_sched_barrier(0);
            // Target super-buffer was read at iter p-1; the barrier at the
            // end of p-1 guarantees all waves are past those reads.
            STASH2((p + 1) & 1);
            __syncthreads();
        }
    }
#undef PREF2
#undef STASH2
#undef PXDECL
#undef WCOMP
#undef FPX2
#undef SPX2
}

// ---------------------------------------------------------------------------
extern "C" void kernel_launch(void* const* d_in, const int* in_sizes, int n_in,
                              void* d_out, int out_size, void* d_ws, size_t ws_size,
                              hipStream_t stream)
{
    const float* features = (const float*)d_in[0];
    const float* flows    = (const float*)d_in[1];
    const float* conv_w   = (const float*)d_in[2];
    float*       out      = (float*)d_out;
    float*       f        = (float*)d_ws;   // [B,2,H,W] = 1 MiB

    downsample_kernel<<<1024, 256, 0, stream>>>(flows, conv_w, f);
    // B * RGN * CGN = 8 * 8 * 16 = 1024 blocks
    warp_kernel<<<1024, 256, 0, stream>>>(features, f, out);
}